// Round 1
// baseline (3414.347 us; speedup 1.0000x reference)
//
#include <hip/hip_runtime.h>
#include <hip/hip_bf16.h>

#define B_   64
#define T_   2048
#define IN_  256
#define H_   128
#define G_   512          // 4*H
#define M_   (B_ * T_)    // 131072

__device__ __forceinline__ float bf2f(unsigned short u) {
    return __uint_as_float(((unsigned int)u) << 16);
}
__device__ __forceinline__ float sigmoid_f(float x) {
    return 1.f / (1.f + __expf(-x));
}
__device__ __forceinline__ float tanh_f(float x) {
    x = fminf(fmaxf(x, -15.f), 15.f);
    float e = __expf(2.f * x);
    return (e - 1.f) / (e + 1.f);
}

// ---------------------------------------------------------------------------
// K1: xp[dir][m][g] = x[m] . w_ih[dir][g] + b_ih[g] + b_hh[g]   (bf16 out)
// M=131072, N=1024 (dir*512+g), K=256.  64x64 tile, 256 thr, 4x4 per thread.
// ---------------------------------------------------------------------------
__global__ __launch_bounds__(256) void gemm_in(
    const float* __restrict__ x,
    const float* __restrict__ w_f, const float* __restrict__ w_b,
    const float* __restrict__ bi_f, const float* __restrict__ bh_f,
    const float* __restrict__ bi_b, const float* __restrict__ bh_b,
    __hip_bfloat16* __restrict__ xp)
{
    const int m0  = blockIdx.x * 64;
    const int n0g = blockIdx.y * 64;        // 0..1023
    const int dir = n0g >> 9;
    const int n0  = n0g & 511;
    const float* __restrict__ w  = dir ? w_b  : w_f;
    const float* __restrict__ bi = dir ? bi_b : bi_f;
    const float* __restrict__ bh = dir ? bh_b : bh_f;

    __shared__ float As[32][68];   // [k][m] transposed
    __shared__ float Bs[32][68];   // [k][n] transposed
    const int tid = threadIdx.x;
    const int tx = tid & 15, ty = tid >> 4;
    float acc[4][4] = {};

    for (int k0 = 0; k0 < 256; k0 += 32) {
        #pragma unroll
        for (int i = 0; i < 2; ++i) {
            int idx = i * 256 + tid;   // 0..511
            int row = idx >> 3;        // 0..63
            int kq  = idx & 7;         // float4 slot
            float4 av = *reinterpret_cast<const float4*>(
                &x[(size_t)(m0 + row) * 256 + k0 + kq * 4]);
            As[kq*4+0][row] = av.x; As[kq*4+1][row] = av.y;
            As[kq*4+2][row] = av.z; As[kq*4+3][row] = av.w;
            float4 bv = *reinterpret_cast<const float4*>(
                &w[(size_t)(n0 + row) * 256 + k0 + kq * 4]);
            Bs[kq*4+0][row] = bv.x; Bs[kq*4+1][row] = bv.y;
            Bs[kq*4+2][row] = bv.z; Bs[kq*4+3][row] = bv.w;
        }
        __syncthreads();
        #pragma unroll
        for (int kk = 0; kk < 32; ++kk) {
            float4 a4 = *reinterpret_cast<const float4*>(&As[kk][ty * 4]);
            float4 b4 = *reinterpret_cast<const float4*>(&Bs[kk][tx * 4]);
            float av[4] = {a4.x, a4.y, a4.z, a4.w};
            float bv[4] = {b4.x, b4.y, b4.z, b4.w};
            #pragma unroll
            for (int i2 = 0; i2 < 4; ++i2)
                #pragma unroll
                for (int j = 0; j < 4; ++j)
                    acc[i2][j] += av[i2] * bv[j];
        }
        __syncthreads();
    }

    #pragma unroll
    for (int i2 = 0; i2 < 4; ++i2) {
        int m = m0 + ty * 4 + i2;
        #pragma unroll
        for (int j = 0; j < 4; ++j) {
            int n = n0 + tx * 4 + j;
            float v = acc[i2][j] + bi[n] + bh[n];
            xp[((size_t)dir * M_ + m) * G_ + n] = __float2bfloat16(v);
        }
    }
}

// ---------------------------------------------------------------------------
// K2: persistent recurrence. 128 WGs = (dir, batch); 512 threads = gate rows.
// w_hh row in VGPRs, h broadcast via LDS, gates exchanged via LDS.
// ---------------------------------------------------------------------------
__global__ __launch_bounds__(512, 2) void lstm_rec(
    const __hip_bfloat16* __restrict__ xp,   // [2][B][T][G]
    const float* __restrict__ w_hh_f,        // [G][H]
    const float* __restrict__ w_hh_b,
    __hip_bfloat16* __restrict__ hs)         // [B][T][2H]
{
    const int wg  = blockIdx.x;
    const int dir = wg >> 6;
    const int b   = wg & 63;
    const int tid = threadIdx.x;   // gate row 0..511
    const float* __restrict__ w_hh = dir ? w_hh_b : w_hh_f;

    float w[H_];
    {
        const float4* wv = reinterpret_cast<const float4*>(w_hh + (size_t)tid * H_);
        #pragma unroll
        for (int k4 = 0; k4 < H_ / 4; ++k4) {
            float4 v = wv[k4];
            w[4*k4+0] = v.x; w[4*k4+1] = v.y; w[4*k4+2] = v.z; w[4*k4+3] = v.w;
        }
    }

    __shared__ float h_lds[H_];
    __shared__ float g_lds[G_];
    if (tid < H_) h_lds[tid] = 0.f;
    float c = 0.f;                 // live only for tid < 128
    __syncthreads();

    const __hip_bfloat16* __restrict__ xb =
        xp + ((size_t)dir * B_ + b) * (size_t)T_ * G_;
    __hip_bfloat16* __restrict__ ho =
        hs + (size_t)b * T_ * (2 * H_) + dir * H_ + tid;

    int t = dir ? (T_ - 1) : 0;
    const int dt = dir ? -1 : 1;
    float gx = __bfloat162float(xb[(size_t)t * G_ + tid]);

    for (int step = 0; step < T_; ++step) {
        float gx_next = 0.f;
        if (step + 1 < T_)
            gx_next = __bfloat162float(xb[(size_t)(t + dt) * G_ + tid]);

        float acc = gx;
        #pragma unroll
        for (int k4 = 0; k4 < H_ / 4; ++k4) {
            float4 h4 = *reinterpret_cast<const float4*>(&h_lds[4 * k4]);
            acc += h4.x * w[4*k4+0];
            acc += h4.y * w[4*k4+1];
            acc += h4.z * w[4*k4+2];
            acc += h4.w * w[4*k4+3];
        }
        g_lds[tid] = acc;
        __syncthreads();

        if (tid < H_) {
            float si = sigmoid_f(g_lds[tid]);
            float sf = sigmoid_f(g_lds[H_ + tid]);
            float tg = tanh_f(g_lds[2 * H_ + tid]);
            float so = sigmoid_f(g_lds[3 * H_ + tid]);
            c = sf * c + si * tg;
            float h = so * tanh_f(c);
            h_lds[tid] = h;
            ho[(size_t)t * (2 * H_)] = __float2bfloat16(h);
        }
        __syncthreads();
        gx = gx_next;
        t += dt;
    }
}

// ---------------------------------------------------------------------------
// K3: out[m][n] = hs[m] . mixer_w[n] + mixer_b[n]  (fp32 out)
// M=131072, N=256, K=256.
// ---------------------------------------------------------------------------
__global__ __launch_bounds__(256) void mixer_gemm(
    const __hip_bfloat16* __restrict__ hs,   // [M][256]
    const float* __restrict__ mw,            // [256][256]
    const float* __restrict__ mb,
    float* __restrict__ out)                 // [M][256]
{
    const int m0 = blockIdx.x * 64;
    const int n0 = blockIdx.y * 64;
    __shared__ float As[32][68];
    __shared__ float Bs[32][68];
    const int tid = threadIdx.x;
    const int tx = tid & 15, ty = tid >> 4;
    float acc[4][4] = {};

    for (int k0 = 0; k0 < 256; k0 += 32) {
        #pragma unroll
        for (int i = 0; i < 2; ++i) {
            int idx = i * 256 + tid;
            int row = idx >> 3;
            int kq  = idx & 7;
            ushort4 a4 = *reinterpret_cast<const ushort4*>(
                &hs[(size_t)(m0 + row) * 256 + k0 + kq * 4]);
            As[kq*4+0][row] = bf2f(a4.x); As[kq*4+1][row] = bf2f(a4.y);
            As[kq*4+2][row] = bf2f(a4.z); As[kq*4+3][row] = bf2f(a4.w);
            float4 bv = *reinterpret_cast<const float4*>(
                &mw[(size_t)(n0 + row) * 256 + k0 + kq * 4]);
            Bs[kq*4+0][row] = bv.x; Bs[kq*4+1][row] = bv.y;
            Bs[kq*4+2][row] = bv.z; Bs[kq*4+3][row] = bv.w;
        }
        __syncthreads();
        #pragma unroll
        for (int kk = 0; kk < 32; ++kk) {
            float4 a4 = *reinterpret_cast<const float4*>(&As[kk][ty * 4]);
            float4 b4 = *reinterpret_cast<const float4*>(&Bs[kk][tx * 4]);
            float av[4] = {a4.x, a4.y, a4.z, a4.w};
            float bv[4] = {b4.x, b4.y, b4.z, b4.w};
            #pragma unroll
            for (int i2 = 0; i2 < 4; ++i2)
                #pragma unroll
                for (int j = 0; j < 4; ++j)
                    acc[i2][j] += av[i2] * bv[j];
        }
        __syncthreads();
    }

    #pragma unroll
    for (int i2 = 0; i2 < 4; ++i2) {
        int m = m0 + ty * 4 + i2;
        float4 o;
        o.x = acc[i2][0] + mb[n0 + tx * 4 + 0];
        o.y = acc[i2][1] + mb[n0 + tx * 4 + 1];
        o.z = acc[i2][2] + mb[n0 + tx * 4 + 2];
        o.w = acc[i2][3] + mb[n0 + tx * 4 + 3];
        *reinterpret_cast<float4*>(&out[(size_t)m * 256 + n0 + tx * 4]) = o;
    }
}

// ---------------------------------------------------------------------------
extern "C" void kernel_launch(void* const* d_in, const int* in_sizes, int n_in,
                              void* d_out, int out_size, void* d_ws, size_t ws_size,
                              hipStream_t stream) {
    const float* x       = (const float*)d_in[0];
    const float* w_ih_f  = (const float*)d_in[1];
    const float* w_hh_f  = (const float*)d_in[2];
    const float* b_ih_f  = (const float*)d_in[3];
    const float* b_hh_f  = (const float*)d_in[4];
    const float* w_ih_b  = (const float*)d_in[5];
    const float* w_hh_b  = (const float*)d_in[6];
    const float* b_ih_b  = (const float*)d_in[7];
    const float* b_hh_b  = (const float*)d_in[8];
    const float* mixer_w = (const float*)d_in[9];
    const float* mixer_b = (const float*)d_in[10];
    float* out = (float*)d_out;

    const size_t xp_bytes = (size_t)2 * M_ * G_ * sizeof(__hip_bfloat16); // 256 MiB
    const size_t hs_bytes = (size_t)M_ * 2 * H_ * sizeof(__hip_bfloat16); //  64 MiB
    if (ws_size < xp_bytes + hs_bytes) return;  // workspace too small: bail visibly

    __hip_bfloat16* xp = (__hip_bfloat16*)d_ws;
    __hip_bfloat16* hs = (__hip_bfloat16*)((char*)d_ws + xp_bytes);

    gemm_in<<<dim3(M_ / 64, 1024 / 64), 256, 0, stream>>>(
        x, w_ih_f, w_ih_b, b_ih_f, b_hh_f, b_ih_b, b_hh_b, xp);
    lstm_rec<<<128, 512, 0, stream>>>(xp, w_hh_f, w_hh_b, hs);
    mixer_gemm<<<dim3(M_ / 64, 256 / 64), 256, 0, stream>>>(
        hs, mixer_w, mixer_b, out);
}

// Round 2
// 2814.964 us; speedup vs baseline: 1.2129x; 1.2129x over previous
//
#include <hip/hip_runtime.h>
#include <hip/hip_bf16.h>

#define B_   64
#define T_   2048
#define IN_  256
#define H_   128
#define G_   512          // 4*H
#define M_   (B_ * T_)    // 131072

typedef _Float16 half2v __attribute__((ext_vector_type(2)));

#if defined(__has_builtin)
#if __has_builtin(__builtin_amdgcn_fdot2)
#define HAVE_FDOT2 1
#endif
#endif

__device__ __forceinline__ float dot2f(half2v a, half2v b, float c) {
#ifdef HAVE_FDOT2
    return __builtin_amdgcn_fdot2(a, b, c, false);
#else
    return c + (float)a.x * (float)b.x + (float)a.y * (float)b.y;
#endif
}
__device__ __forceinline__ half2v c2(float f) {
    return __builtin_bit_cast(half2v, f);
}
__device__ __forceinline__ float packh2(float a, float b) {
    half2v h; h.x = (_Float16)a; h.y = (_Float16)b;
    return __builtin_bit_cast(float, h);
}
__device__ __forceinline__ float bf2f(unsigned short u) {
    return __uint_as_float(((unsigned int)u) << 16);
}
__device__ __forceinline__ float tanh_f(float x) {
    x = fminf(fmaxf(x, -15.f), 15.f);
    float e = __expf(2.f * x);
    return (e - 1.f) / (e + 1.f);
}

// ---------------------------------------------------------------------------
// K1: xp[dir][m][g] = x[m] . w_ih[dir][g] + b_ih[g] + b_hh[g]   (bf16 out)
// ---------------------------------------------------------------------------
__global__ __launch_bounds__(256) void gemm_in(
    const float* __restrict__ x,
    const float* __restrict__ w_f, const float* __restrict__ w_b,
    const float* __restrict__ bi_f, const float* __restrict__ bh_f,
    const float* __restrict__ bi_b, const float* __restrict__ bh_b,
    __hip_bfloat16* __restrict__ xp)
{
    const int m0  = blockIdx.x * 64;
    const int n0g = blockIdx.y * 64;
    const int dir = n0g >> 9;
    const int n0  = n0g & 511;
    const float* __restrict__ w  = dir ? w_b  : w_f;
    const float* __restrict__ bi = dir ? bi_b : bi_f;
    const float* __restrict__ bh = dir ? bh_b : bh_f;

    __shared__ float As[32][68];
    __shared__ float Bs[32][68];
    const int tid = threadIdx.x;
    const int tx = tid & 15, ty = tid >> 4;
    float acc[4][4] = {};

    for (int k0 = 0; k0 < 256; k0 += 32) {
        #pragma unroll
        for (int i = 0; i < 2; ++i) {
            int idx = i * 256 + tid;
            int row = idx >> 3;
            int kq  = idx & 7;
            float4 av = *reinterpret_cast<const float4*>(
                &x[(size_t)(m0 + row) * 256 + k0 + kq * 4]);
            As[kq*4+0][row] = av.x; As[kq*4+1][row] = av.y;
            As[kq*4+2][row] = av.z; As[kq*4+3][row] = av.w;
            float4 bv = *reinterpret_cast<const float4*>(
                &w[(size_t)(n0 + row) * 256 + k0 + kq * 4]);
            Bs[kq*4+0][row] = bv.x; Bs[kq*4+1][row] = bv.y;
            Bs[kq*4+2][row] = bv.z; Bs[kq*4+3][row] = bv.w;
        }
        __syncthreads();
        #pragma unroll
        for (int kk = 0; kk < 32; ++kk) {
            float4 a4 = *reinterpret_cast<const float4*>(&As[kk][ty * 4]);
            float4 b4 = *reinterpret_cast<const float4*>(&Bs[kk][tx * 4]);
            float av[4] = {a4.x, a4.y, a4.z, a4.w};
            float bv[4] = {b4.x, b4.y, b4.z, b4.w};
            #pragma unroll
            for (int i2 = 0; i2 < 4; ++i2)
                #pragma unroll
                for (int j = 0; j < 4; ++j)
                    acc[i2][j] += av[i2] * bv[j];
        }
        __syncthreads();
    }

    #pragma unroll
    for (int i2 = 0; i2 < 4; ++i2) {
        int m = m0 + ty * 4 + i2;
        #pragma unroll
        for (int j = 0; j < 4; ++j) {
            int n = n0 + tx * 4 + j;
            float v = acc[i2][j] + bi[n] + bh[n];
            xp[((size_t)dir * M_ + m) * G_ + n] = __float2bfloat16(v);
        }
    }
}

// ---------------------------------------------------------------------------
// K2: persistent recurrence. 128 WGs = (dir, batch); 512 threads.
// tid = j*4 + g : j = cell index 0..127, g = gate type (0=i,1=f,2=g,3=o).
// W row (128 fp16) in 16 NAMED float4 registers; dot via v_dot2_f32_f16.
// Gate exchange via quad shfl_xor butterfly; h double-buffered in LDS;
// ONE barrier per step.
// ---------------------------------------------------------------------------
__global__ __launch_bounds__(512, 2) void lstm_rec(
    const __hip_bfloat16* __restrict__ xp,   // [2][B][T][G]
    const float* __restrict__ w_hh_f,        // [G][H]
    const float* __restrict__ w_hh_b,
    __hip_bfloat16* __restrict__ hs)         // [B][T][2H]
{
    const int wg  = blockIdx.x;
    const int dir = wg >> 6;
    const int b   = wg & 63;
    const int tid = threadIdx.x;
    const int j   = tid >> 2;      // cell index 0..127
    const int g   = tid & 3;       // gate type
    const int grow = g * H_ + j;   // row in [G]
    const float* __restrict__ w_hh = dir ? w_hh_b : w_hh_f;

    // ---- load W row, convert to fp16, keep in 16 named float4 (64 VGPRs) --
    const float4* wv4 = reinterpret_cast<const float4*>(w_hh + (size_t)grow * H_);
#define LOADW(q) float4 W##q; { float4 r0 = wv4[2*(q)], r1 = wv4[2*(q)+1]; \
    W##q.x = packh2(r0.x, r0.y); W##q.y = packh2(r0.z, r0.w); \
    W##q.z = packh2(r1.x, r1.y); W##q.w = packh2(r1.z, r1.w); }
    LOADW(0)  LOADW(1)  LOADW(2)  LOADW(3)
    LOADW(4)  LOADW(5)  LOADW(6)  LOADW(7)
    LOADW(8)  LOADW(9)  LOADW(10) LOADW(11)
    LOADW(12) LOADW(13) LOADW(14) LOADW(15)
#undef LOADW

    __shared__ alignas(16) _Float16 hbuf[2][H_];
    if (tid < H_) { hbuf[0][tid] = (_Float16)0.f; hbuf[1][tid] = (_Float16)0.f; }
    float c = 0.f;
    __syncthreads();

    const __hip_bfloat16* __restrict__ xb =
        xp + ((size_t)dir * B_ + b) * (size_t)T_ * G_;
    __hip_bfloat16* __restrict__ ho =
        hs + (size_t)b * T_ * (2 * H_) + dir * H_ + j;

    int t = dir ? (T_ - 1) : 0;
    const int dt = dir ? -1 : 1;
    float gx = bf2f(*reinterpret_cast<const unsigned short*>(&xb[(size_t)t * G_ + grow]));
    const float sc = (g == 2) ? 1.f : 0.5f;   // tanh for g-gate, sigmoid via tanh else

    for (int step = 0; step < T_; ++step) {
        // prefetch next step's gate preactivation (hides HBM latency)
        float gx_next = 0.f;
        if (step + 1 < T_)
            gx_next = bf2f(*reinterpret_cast<const unsigned short*>(
                &xb[(size_t)(t + dt) * G_ + grow]));

        const float4* hv4 = reinterpret_cast<const float4*>(hbuf[step & 1]);
        float a0 = gx, a1 = 0.f, a2 = 0.f, a3 = 0.f;
#define DOTQ(q) { float4 Hq = hv4[q]; \
        a0 = dot2f(c2(W##q.x), c2(Hq.x), a0); \
        a1 = dot2f(c2(W##q.y), c2(Hq.y), a1); \
        a2 = dot2f(c2(W##q.z), c2(Hq.z), a2); \
        a3 = dot2f(c2(W##q.w), c2(Hq.w), a3); }
        DOTQ(0)  DOTQ(1)  DOTQ(2)  DOTQ(3)
        DOTQ(4)  DOTQ(5)  DOTQ(6)  DOTQ(7)
        DOTQ(8)  DOTQ(9)  DOTQ(10) DOTQ(11)
        DOTQ(12) DOTQ(13) DOTQ(14) DOTQ(15)
#undef DOTQ
        float pre = (a0 + a1) + (a2 + a3);

        // activate own gate (uniform tanh path; sigmoid = 0.5*tanh(x/2)+0.5)
        float tv  = tanh_f(pre * sc);
        float act = (g == 2) ? tv : 0.5f * tv + 0.5f;

        // quad butterfly: collect all 4 activated gates
        float e1 = __shfl_xor(act, 1);
        float e2 = __shfl_xor(act, 2);
        float e3 = __shfl_xor(e1, 2);
        // value for gate q is: q==g -> act, q==g^1 -> e1, q==g^2 -> e2, q==g^3 -> e3
        float si = (g==0)?act:(g==1)?e1:(g==2)?e2:e3;
        float sf = (g==1)?act:(g==0)?e1:(g==3)?e2:e3;
        float tg = (g==2)?act:(g==3)?e1:(g==0)?e2:e3;
        float so = (g==3)?act:(g==2)?e1:(g==1)?e2:e3;

        c = sf * c + si * tg;
        float h = so * tanh_f(c);

        if (g == 0) {
            hbuf[(step & 1) ^ 1][j] = (_Float16)h;
            ho[(size_t)t * (2 * H_)] = __float2bfloat16(h);
        }
        __syncthreads();
        gx = gx_next;
        t += dt;
    }
}

// ---------------------------------------------------------------------------
// K3: out[m][n] = hs[m] . mixer_w[n] + mixer_b[n]  (fp32 out)
// ---------------------------------------------------------------------------
__global__ __launch_bounds__(256) void mixer_gemm(
    const __hip_bfloat16* __restrict__ hs,   // [M][256]
    const float* __restrict__ mw,            // [256][256]
    const float* __restrict__ mb,
    float* __restrict__ out)                 // [M][256]
{
    const int m0 = blockIdx.x * 64;
    const int n0 = blockIdx.y * 64;
    __shared__ float As[32][68];
    __shared__ float Bs[32][68];
    const int tid = threadIdx.x;
    const int tx = tid & 15, ty = tid >> 4;
    float acc[4][4] = {};

    for (int k0 = 0; k0 < 256; k0 += 32) {
        #pragma unroll
        for (int i = 0; i < 2; ++i) {
            int idx = i * 256 + tid;
            int row = idx >> 3;
            int kq  = idx & 7;
            ushort4 a4 = *reinterpret_cast<const ushort4*>(
                &hs[(size_t)(m0 + row) * 256 + k0 + kq * 4]);
            As[kq*4+0][row] = bf2f(a4.x); As[kq*4+1][row] = bf2f(a4.y);
            As[kq*4+2][row] = bf2f(a4.z); As[kq*4+3][row] = bf2f(a4.w);
            float4 bv = *reinterpret_cast<const float4*>(
                &mw[(size_t)(n0 + row) * 256 + k0 + kq * 4]);
            Bs[kq*4+0][row] = bv.x; Bs[kq*4+1][row] = bv.y;
            Bs[kq*4+2][row] = bv.z; Bs[kq*4+3][row] = bv.w;
        }
        __syncthreads();
        #pragma unroll
        for (int kk = 0; kk < 32; ++kk) {
            float4 a4 = *reinterpret_cast<const float4*>(&As[kk][ty * 4]);
            float4 b4 = *reinterpret_cast<const float4*>(&Bs[kk][tx * 4]);
            float av[4] = {a4.x, a4.y, a4.z, a4.w};
            float bv[4] = {b4.x, b4.y, b4.z, b4.w};
            #pragma unroll
            for (int i2 = 0; i2 < 4; ++i2)
                #pragma unroll
                for (int j = 0; j < 4; ++j)
                    acc[i2][j] += av[i2] * bv[j];
        }
        __syncthreads();
    }

    #pragma unroll
    for (int i2 = 0; i2 < 4; ++i2) {
        int m = m0 + ty * 4 + i2;
        float4 o;
        o.x = acc[i2][0] + mb[n0 + tx * 4 + 0];
        o.y = acc[i2][1] + mb[n0 + tx * 4 + 1];
        o.z = acc[i2][2] + mb[n0 + tx * 4 + 2];
        o.w = acc[i2][3] + mb[n0 + tx * 4 + 3];
        *reinterpret_cast<float4*>(&out[(size_t)m * 256 + n0 + tx * 4]) = o;
    }
}

// ---------------------------------------------------------------------------
extern "C" void kernel_launch(void* const* d_in, const int* in_sizes, int n_in,
                              void* d_out, int out_size, void* d_ws, size_t ws_size,
                              hipStream_t stream) {
    const float* x       = (const float*)d_in[0];
    const float* w_ih_f  = (const float*)d_in[1];
    const float* w_hh_f  = (const float*)d_in[2];
    const float* b_ih_f  = (const float*)d_in[3];
    const float* b_hh_f  = (const float*)d_in[4];
    const float* w_ih_b  = (const float*)d_in[5];
    const float* w_hh_b  = (const float*)d_in[6];
    const float* b_ih_b  = (const float*)d_in[7];
    const float* b_hh_b  = (const float*)d_in[8];
    const float* mixer_w = (const float*)d_in[9];
    const float* mixer_b = (const float*)d_in[10];
    float* out = (float*)d_out;

    const size_t xp_bytes = (size_t)2 * M_ * G_ * sizeof(__hip_bfloat16); // 256 MiB
    const size_t hs_bytes = (size_t)M_ * 2 * H_ * sizeof(__hip_bfloat16); //  64 MiB
    if (ws_size < xp_bytes + hs_bytes) return;

    __hip_bfloat16* xp = (__hip_bfloat16*)d_ws;
    __hip_bfloat16* hs = (__hip_bfloat16*)((char*)d_ws + xp_bytes);

    gemm_in<<<dim3(M_ / 64, 1024 / 64), 256, 0, stream>>>(
        x, w_ih_f, w_ih_b, b_ih_f, b_hh_f, b_ih_b, b_hh_b, xp);
    lstm_rec<<<128, 512, 0, stream>>>(xp, w_hh_f, w_hh_b, hs);
    mixer_gemm<<<dim3(M_ / 64, 256 / 64), 256, 0, stream>>>(
        hs, mixer_w, mixer_b, out);
}